// Round 1
// baseline (261.531 us; speedup 1.0000x reference)
//
#include <hip/hip_runtime.h>
#include <math.h>

#define KK 32
#define DD 256
#define QQ 16
#define NN 8192
#define TN 16
#define LOG2PI 1.8378770664093453f

// ---------------- Kernel 1: per-component precompute (one block per k) ----
// Builds T[k][d][q] = inv_a[d] * sum_{q'<=q} Linv[q][q'] * Lambda[k][d][q']
// and constk[k] = log_pi[k] - 0.5*(D*log2pi + logdetC_k)
__global__ __launch_bounds__(256) void mfa_setup_k(
    const float* __restrict__ log_pi,
    const float* __restrict__ Lambda,   // [K][D][Q]
    const float* __restrict__ log_psi,  // [D]
    float* __restrict__ T,              // [K][D][Q]
    float* __restrict__ constk)         // [K]
{
    __shared__ float inv_a_s[DD];
    __shared__ float Ls[DD][QQ];        // Lambda_k
    __shared__ float Ms[QQ][QQ + 1];    // M then Cholesky L (in-place, lower)
    __shared__ float Li[QQ][QQ + 1];    // L^-1 (lower)
    __shared__ float red[4];
    __shared__ float sum_log_a_s;

    const int k = blockIdx.x;
    const int tid = threadIdx.x;

    // a_d = exp(log_psi)+1e-6+1e-5 ; reduce sum log a
    float a = expf(log_psi[tid]) + 1e-6f + 1e-5f;
    inv_a_s[tid] = 1.0f / a;
    float lg = logf(a);
    #pragma unroll
    for (int off = 32; off; off >>= 1) lg += __shfl_down(lg, off, 64);
    if ((tid & 63) == 0) red[tid >> 6] = lg;
    __syncthreads();
    if (tid == 0) sum_log_a_s = red[0] + red[1] + red[2] + red[3];

    // stage Lambda_k
    const float* Lk = Lambda + (size_t)k * DD * QQ;
    for (int i = tid; i < DD * QQ; i += 256) Ls[i >> 4][i & 15] = Lk[i];
    __syncthreads();

    // M = I + Lambda^T diag(inv_a) Lambda : thread -> (q1,q2)
    {
        const int q1 = tid >> 4, q2 = tid & 15;
        float b = 0.f;
        for (int d = 0; d < DD; ++d) b += Ls[d][q1] * Ls[d][q2] * inv_a_s[d];
        Ms[q1][q2] = b + (q1 == q2 ? 1.0f : 0.0f);
    }
    __syncthreads();

    if (tid == 0) {
        // in-place Cholesky (lower), 16x16 serial
        for (int j = 0; j < QQ; ++j) {
            float s = Ms[j][j];
            for (int m = 0; m < j; ++m) s -= Ms[j][m] * Ms[j][m];
            const float ljj = sqrtf(s);
            Ms[j][j] = ljj;
            const float inv = 1.0f / ljj;
            for (int i = j + 1; i < QQ; ++i) {
                float t = Ms[i][j];
                for (int m = 0; m < j; ++m) t -= Ms[i][m] * Ms[j][m];
                Ms[i][j] = t * inv;
            }
        }
        // Linv by forward substitution, column j
        for (int j = 0; j < QQ; ++j) {
            for (int i = 0; i < j; ++i) Li[i][j] = 0.f;
            Li[j][j] = 1.0f / Ms[j][j];
            for (int i = j + 1; i < QQ; ++i) {
                float t = 0.f;
                for (int m = j; m < i; ++m) t -= Ms[i][m] * Li[m][j];
                Li[i][j] = t / Ms[i][i];
            }
        }
        float ld = 0.f;
        for (int j = 0; j < QQ; ++j) ld += logf(Ms[j][j]);
        const float logdetC = sum_log_a_s + 2.0f * ld;
        constk[k] = log_pi[k] - 0.5f * ((float)DD * LOG2PI + logdetC);
    }
    __syncthreads();

    // T row for d = tid
    {
        const int d = tid;
        float lam[QQ];
        #pragma unroll
        for (int q = 0; q < QQ; ++q) lam[q] = Ls[d][q];
        const float ia = inv_a_s[d];
        float4* Td = (float4*)(T + ((size_t)k * DD + d) * QQ);
        float tv[QQ];
        #pragma unroll
        for (int q = 0; q < QQ; ++q) {
            float t = 0.f;
            for (int qp = 0; qp <= q; ++qp) t += Li[q][qp] * lam[qp];
            tv[q] = t * ia;
        }
        Td[0] = make_float4(tv[0], tv[1], tv[2], tv[3]);
        Td[1] = make_float4(tv[4], tv[5], tv[6], tv[7]);
        Td[2] = make_float4(tv[8], tv[9], tv[10], tv[11]);
        Td[3] = make_float4(tv[12], tv[13], tv[14], tv[15]);
    }
}

// ---------------- Kernel 2: main scoring + fused logsumexp ---------------
// Block: 16 points x all 32 components. Thread p -> (n = p&15, k = p>>4),
// two pairs per thread.
__global__ __launch_bounds__(256) void mfa_main_k(
    const float* __restrict__ X,        // [N][D]
    const float* __restrict__ mu,       // [K][D]
    const float* __restrict__ log_psi,  // [D]
    const float* __restrict__ T,        // [K][D][Q]
    const float* __restrict__ constk,   // [K]
    float* __restrict__ out)            // [N*K] then [N]
{
    __shared__ __align__(16) float inv_a_s[DD];
    __shared__ float Xs[TN][DD + 1];    // +1 pad: bank (n+d)%32, conflict-free
    __shared__ float maha_s[TN][KK + 1];
    __shared__ float const_s[KK];

    const int tid = threadIdx.x;
    const int n0 = blockIdx.x * TN;

    inv_a_s[tid] = 1.0f / (expf(log_psi[tid]) + 1e-6f + 1e-5f);
    if (tid < KK) const_s[tid] = constk[tid];

    // stage X tile (coalesced float4)
    {
        const float4* Xb = (const float4*)(X + (size_t)n0 * DD);
        #pragma unroll
        for (int i = tid; i < TN * DD / 4; i += 256) {
            float4 v = Xb[i];
            const int n = i >> 6;           // (i*4)/256
            const int d = (i & 63) << 2;
            Xs[n][d + 0] = v.x; Xs[n][d + 1] = v.y;
            Xs[n][d + 2] = v.z; Xs[n][d + 3] = v.w;
        }
    }
    __syncthreads();

    const float4* ia4p = (const float4*)inv_a_s;

    for (int p = tid; p < TN * KK; p += 256) {
        const int n = p & (TN - 1);
        const int k = p >> 4;
        const float4* mk4 = (const float4*)(mu + (size_t)k * DD);
        const float4* Tk = (const float4*)(T + (size_t)k * DD * QQ);
        float s = 0.f;
        float z[QQ];
        #pragma unroll
        for (int q = 0; q < QQ; ++q) z[q] = 0.f;

        for (int d4 = 0; d4 < DD / 4; ++d4) {
            const float4 m4 = mk4[d4];
            const float4 ia = ia4p[d4];
            const int d = d4 << 2;
            float diff[4];
            diff[0] = Xs[n][d + 0] - m4.x;
            diff[1] = Xs[n][d + 1] - m4.y;
            diff[2] = Xs[n][d + 2] - m4.z;
            diff[3] = Xs[n][d + 3] - m4.w;
            s = fmaf(diff[0] * ia.x, diff[0], s);
            s = fmaf(diff[1] * ia.y, diff[1], s);
            s = fmaf(diff[2] * ia.z, diff[2], s);
            s = fmaf(diff[3] * ia.w, diff[3], s);
            #pragma unroll
            for (int dd = 0; dd < 4; ++dd) {
                const float df = diff[dd];
                const float4 t0 = Tk[(d + dd) * 4 + 0];
                const float4 t1 = Tk[(d + dd) * 4 + 1];
                const float4 t2 = Tk[(d + dd) * 4 + 2];
                const float4 t3 = Tk[(d + dd) * 4 + 3];
                z[0]  = fmaf(t0.x, df, z[0]);  z[1]  = fmaf(t0.y, df, z[1]);
                z[2]  = fmaf(t0.z, df, z[2]);  z[3]  = fmaf(t0.w, df, z[3]);
                z[4]  = fmaf(t1.x, df, z[4]);  z[5]  = fmaf(t1.y, df, z[5]);
                z[6]  = fmaf(t1.z, df, z[6]);  z[7]  = fmaf(t1.w, df, z[7]);
                z[8]  = fmaf(t2.x, df, z[8]);  z[9]  = fmaf(t2.y, df, z[9]);
                z[10] = fmaf(t2.z, df, z[10]); z[11] = fmaf(t2.w, df, z[11]);
                z[12] = fmaf(t3.x, df, z[12]); z[13] = fmaf(t3.w == t3.w ? t3.w : t3.w, 0.f, z[13]); // placeholder avoided below
                z[13] = fmaf(t3.y, df, z[13] - 0.f);
                z[14] = fmaf(t3.z, df, z[14]); z[15] = fmaf(t3.w, df, z[15]);
            }
        }
        float corr = 0.f;
        #pragma unroll
        for (int q = 0; q < QQ; ++q) corr = fmaf(z[q], z[q], corr);
        maha_s[n][k] = s - corr;
    }
    __syncthreads();

    // fused logsumexp + output, one thread per point
    if (tid < TN) {
        const int n = tid;
        float lp[KK];
        float m = -INFINITY;
        #pragma unroll
        for (int k = 0; k < KK; ++k) {
            const float v = const_s[k] - 0.5f * maha_s[n][k];
            lp[k] = v;
            m = fmaxf(m, v);
        }
        float sum = 0.f;
        #pragma unroll
        for (int k = 0; k < KK; ++k) sum += expf(lp[k] - m);
        const float lse = m + logf(sum);
        float4* o = (float4*)(out + (size_t)(n0 + n) * KK);
        #pragma unroll
        for (int k4 = 0; k4 < KK / 4; ++k4)
            o[k4] = make_float4(lp[4 * k4] - lse, lp[4 * k4 + 1] - lse,
                                lp[4 * k4 + 2] - lse, lp[4 * k4 + 3] - lse);
        out[(size_t)NN * KK + n0 + n] = lse;
    }
}

extern "C" void kernel_launch(void* const* d_in, const int* in_sizes, int n_in,
                              void* d_out, int out_size, void* d_ws, size_t ws_size,
                              hipStream_t stream) {
    const float* X       = (const float*)d_in[0];
    const float* log_pi  = (const float*)d_in[1];
    const float* mu      = (const float*)d_in[2];
    const float* Lambda  = (const float*)d_in[3];
    const float* log_psi = (const float*)d_in[4];
    float* out = (float*)d_out;

    float* T      = (float*)d_ws;                 // K*D*Q floats = 512 KB
    float* constk = T + (size_t)KK * DD * QQ;     // K floats

    mfa_setup_k<<<KK, 256, 0, stream>>>(log_pi, Lambda, log_psi, T, constk);
    mfa_main_k<<<NN / TN, 256, 0, stream>>>(X, mu, log_psi, T, constk, out);
}

// Round 2
// 101.296 us; speedup vs baseline: 2.5818x; 2.5818x over previous
//
#include <hip/hip_runtime.h>
#include <math.h>

#define KK 32
#define DD 256
#define QQ 16
#define NN 8192
#define LOG2PI 1.8378770664093453f
#define NCT 36            // padded col-tiles: 576 cols = 512 z + 32 xmu + 32 pad
#define GS_STRIDE 580     // LDS row stride (words): 580 % 32 == 4 -> 2-way max on C-stores

typedef __attribute__((ext_vector_type(8))) short short8v;
typedef __attribute__((ext_vector_type(4))) float float4v;

__device__ __forceinline__ unsigned short f2bf(float f) {
    union { float f; unsigned int u; } v; v.f = f;
    unsigned int u = v.u;
    return (unsigned short)((u + 0x7FFFu + ((u >> 16) & 1u)) >> 16);  // RNE
}

// ---------------- Kernel 1: per-component precompute (one block per k) ----
// Writes Wb (bf16, MFMA B-frag layout), constk2[k], wvec[k][q].
// Wb logical: W[d][c]; c in [0,512): k=c>>4,q=c&15 -> T_k[q][d];
//             c in [512,544): mu[c-512][d]*inv_a[d]; c>=544: 0.
// Frag layout: Wb[((kt*NCT+ct)*64+lane)*8+j] = W[kt*32+(lane>>4)*8+j][ct*16+(lane&15)]
__global__ __launch_bounds__(256) void mfa_setup_k(
    const float* __restrict__ log_pi,
    const float* __restrict__ mu,       // [K][D]
    const float* __restrict__ Lambda,   // [K][D][Q]
    const float* __restrict__ log_psi,  // [D]
    unsigned short* __restrict__ Wb,    // [8][NCT][64][8] bf16
    float* __restrict__ constk2,        // [K]
    float* __restrict__ wvec)           // [K][Q]
{
    __shared__ float inv_a_s[DD];
    __shared__ float Ls[DD][QQ];
    __shared__ float Ms[QQ][QQ + 1];
    __shared__ float Lc[QQ][QQ + 1];
    __shared__ float Li[QQ][QQ + 1];
    __shared__ float red_lg[4], red_m2[4], redq[4][QQ];
    __shared__ float sum_log_a_s, mu2a_s;

    const int k = blockIdx.x;
    const int tid = threadIdx.x;
    const int wv = tid >> 6;

    const float a = expf(log_psi[tid]) + 1e-6f + 1e-5f;
    const float ia = 1.0f / a;
    inv_a_s[tid] = ia;
    const float mud = mu[k * DD + tid];

    // wave+block reduce: sum log a, sum mu^2/a
    float lg = logf(a);
    float m2 = mud * mud * ia;
    #pragma unroll
    for (int off = 32; off; off >>= 1) {
        lg += __shfl_down(lg, off, 64);
        m2 += __shfl_down(m2, off, 64);
    }
    if ((tid & 63) == 0) { red_lg[wv] = lg; red_m2[wv] = m2; }

    // stage Lambda_k
    const float* Lk = Lambda + (size_t)k * DD * QQ;
    for (int i = tid; i < DD * QQ; i += 256) Ls[i >> 4][i & 15] = Lk[i];
    __syncthreads();
    if (tid == 0) {
        sum_log_a_s = red_lg[0] + red_lg[1] + red_lg[2] + red_lg[3];
        mu2a_s      = red_m2[0] + red_m2[1] + red_m2[2] + red_m2[3];
    }

    // M = I + Lambda^T diag(inv_a) Lambda
    {
        const int q1 = tid >> 4, q2 = tid & 15;
        float b = 0.f;
        for (int d = 0; d < DD; ++d) b += Ls[d][q1] * Ls[d][q2] * inv_a_s[d];
        Ms[q1][q2] = b + (q1 == q2 ? 1.0f : 0.0f);
    }
    __syncthreads();

    // wave-parallel Cholesky (lower) into Lc: lane i handles row i of column j
    for (int j = 0; j < QQ; ++j) {
        float s_i = 0.f;
        if (tid < QQ && tid >= j) {
            s_i = Ms[tid][j];
            for (int t = 0; t < j; ++t) s_i -= Lc[tid][t] * Lc[j][t];
        }
        if (tid == j) Lc[j][j] = sqrtf(s_i);
        __syncthreads();
        if (tid < QQ && tid > j) Lc[tid][j] = s_i / Lc[j][j];
        __syncthreads();
    }

    // L^-1: column c per thread, forward substitution
    if (tid < QQ) {
        const int c = tid;
        for (int i = 0; i < c; ++i) Li[i][c] = 0.f;
        Li[c][c] = 1.0f / Lc[c][c];
        for (int i = c + 1; i < QQ; ++i) {
            float t = 0.f;
            for (int m = c; m < i; ++m) t -= Lc[i][m] * Li[m][c];
            Li[i][c] = t / Lc[i][i];
        }
    }
    __syncthreads();

    if (tid == 0) {
        float ld = 0.f;
        for (int j = 0; j < QQ; ++j) ld += logf(Lc[j][j]);
        const float logdetC = sum_log_a_s + 2.0f * ld;
        constk2[k] = log_pi[k] - 0.5f * ((float)DD * LOG2PI + logdetC + mu2a_s);
    }

    // T row for d = tid: tv[q] = inv_a[d] * sum_{qp<=q} Li[q][qp]*Lambda[d][qp]
    float tv[QQ];
    {
        float lam[QQ];
        #pragma unroll
        for (int q = 0; q < QQ; ++q) lam[q] = Ls[tid][q];
        #pragma unroll
        for (int q = 0; q < QQ; ++q) {
            float t = 0.f;
            for (int qp = 0; qp <= q; ++qp) t += Li[q][qp] * lam[qp];
            tv[q] = t * ia;
        }
    }

    // w_kq = sum_d tv[q] * mu[k][d]
    #pragma unroll
    for (int q = 0; q < QQ; ++q) {
        float v = tv[q] * mud;
        #pragma unroll
        for (int off = 32; off; off >>= 1) v += __shfl_down(v, off, 64);
        if ((tid & 63) == 0) redq[wv][q] = v;
    }
    __syncthreads();
    if (tid < QQ) wvec[k * QQ + tid] = redq[0][tid] + redq[1][tid] + redq[2][tid] + redq[3][tid];

    // scatter into Wb fragment layout (bf16)
    {
        const int d = tid;
        const int kt = d >> 5, l_hi = (d >> 3) & 3, j = d & 7;
        #pragma unroll
        for (int q = 0; q < QQ; ++q) {
            const size_t idx = (((size_t)(kt * NCT + k) * 64) + l_hi * 16 + q) * 8 + j;
            Wb[idx] = f2bf(tv[q]);
        }
        // xmu column: c = 512 + k -> ct = 32 + (k>>4), lane&15 = k&15
        const size_t idx = (((size_t)(kt * NCT + 32 + (k >> 4)) * 64) + l_hi * 16 + (k & 15)) * 8 + j;
        Wb[idx] = f2bf(mud * ia);
    }
    // zero the pad col-tiles (ct 34, 35): blocks 0 and 1
    if (k < 2) {
        for (int i = tid; i < 512; i += 256) {
            const int kt = i >> 6, lane = i & 63;
            const size_t base = ((size_t)(kt * NCT + 34 + k) * 64 + lane) * 8;
            #pragma unroll
            for (int j = 0; j < 8; ++j) Wb[base + j] = 0;
        }
    }
}

// ---------------- Kernel 2: fused GEMM + epilogue ------------------------
// Block: 32 rows x 576 cols, 4 waves; wave w owns col-tiles [9w, 9w+9).
__global__ __launch_bounds__(256) void mfa_gemm_fused(
    const float* __restrict__ X,        // [N][D]
    const float* __restrict__ log_psi,  // [D]
    const unsigned short* __restrict__ Wb,
    const float* __restrict__ constk2,
    const float* __restrict__ wvec,     // [K][Q]
    float* __restrict__ out)            // [N*K] then [N]
{
    __shared__ float inv_a_s[DD];
    __shared__ float Gs[32][GS_STRIDE];
    __shared__ float w_s[KK][QQ];
    __shared__ float lps[32][KK + 1];
    __shared__ float sx_s[32];
    __shared__ float ck_s[KK];

    const int tid = threadIdx.x;
    const int lane = tid & 63, wv = tid >> 6;
    const int r0 = blockIdx.x * 32;

    inv_a_s[tid] = 1.0f / (expf(log_psi[tid]) + 1e-6f + 1e-5f);
    if (tid < KK) ck_s[tid] = constk2[tid];
    for (int i = tid; i < KK * QQ; i += 256) ((float*)w_s)[i] = wvec[i];
    __syncthreads();

    // ---- MFMA K-loop (no LDS) ----
    const int sw = wv * 9;
    float4v acc[2][9];
    #pragma unroll
    for (int rt = 0; rt < 2; ++rt)
        #pragma unroll
        for (int ct = 0; ct < 9; ++ct)
            #pragma unroll
            for (int r = 0; r < 4; ++r) acc[rt][ct][r] = 0.f;

    const int rA = r0 + (lane & 15);
    const int kq = (lane >> 4) * 8;
    const float* Xrow0 = X + (size_t)rA * DD;
    const float* Xrow1 = X + (size_t)(rA + 16) * DD;

    #pragma unroll
    for (int kt = 0; kt < 8; ++kt) {
        const int dbase = kt * 32 + kq;
        short8v bf[9];
        const short8v* Wp = (const short8v*)Wb + (size_t)(kt * NCT + sw) * 64 + lane;
        #pragma unroll
        for (int ct = 0; ct < 9; ++ct) bf[ct] = Wp[ct * 64];

        const float4 xa0 = *(const float4*)(Xrow0 + dbase);
        const float4 xa1 = *(const float4*)(Xrow0 + dbase + 4);
        const float4 xb0 = *(const float4*)(Xrow1 + dbase);
        const float4 xb1 = *(const float4*)(Xrow1 + dbase + 4);
        short8v a0, a1;
        a0[0] = (short)f2bf(xa0.x); a0[1] = (short)f2bf(xa0.y);
        a0[2] = (short)f2bf(xa0.z); a0[3] = (short)f2bf(xa0.w);
        a0[4] = (short)f2bf(xa1.x); a0[5] = (short)f2bf(xa1.y);
        a0[6] = (short)f2bf(xa1.z); a0[7] = (short)f2bf(xa1.w);
        a1[0] = (short)f2bf(xb0.x); a1[1] = (short)f2bf(xb0.y);
        a1[2] = (short)f2bf(xb0.z); a1[3] = (short)f2bf(xb0.w);
        a1[4] = (short)f2bf(xb1.x); a1[5] = (short)f2bf(xb1.y);
        a1[6] = (short)f2bf(xb1.z); a1[7] = (short)f2bf(xb1.w);

        #pragma unroll
        for (int ct = 0; ct < 9; ++ct) {
            acc[0][ct] = __builtin_amdgcn_mfma_f32_16x16x32_bf16(a0, bf[ct], acc[0][ct], 0, 0, 0);
            acc[1][ct] = __builtin_amdgcn_mfma_f32_16x16x32_bf16(a1, bf[ct], acc[1][ct], 0, 0, 0);
        }
    }

    // ---- C -> LDS (pad stride => 2-way max, free) ----
    {
        const int crow = (lane >> 4) * 4;
        const int ccol = lane & 15;
        #pragma unroll
        for (int rt = 0; rt < 2; ++rt)
            #pragma unroll
            for (int ct = 0; ct < 9; ++ct) {
                const int col = (sw + ct) * 16 + ccol;
                #pragma unroll
                for (int r = 0; r < 4; ++r)
                    Gs[rt * 16 + crow + r][col] = acc[rt][ct][r];
            }
    }

    // ---- sx[n] = sum_d x^2 * inv_a (f32), 8 threads per row ----
    {
        const int n = tid >> 3, part = tid & 7;
        const float4* xp = (const float4*)(X + (size_t)(r0 + n) * DD + part * 32);
        float s = 0.f;
        #pragma unroll
        for (int i = 0; i < 8; ++i) {
            const float4 v = xp[i];
            const int d = part * 32 + i * 4;
            s = fmaf(v.x * inv_a_s[d + 0], v.x, s);
            s = fmaf(v.y * inv_a_s[d + 1], v.y, s);
            s = fmaf(v.z * inv_a_s[d + 2], v.z, s);
            s = fmaf(v.w * inv_a_s[d + 3], v.w, s);
        }
        s += __shfl_xor(s, 1, 64);
        s += __shfl_xor(s, 2, 64);
        s += __shfl_xor(s, 4, 64);
        if (part == 0) sx_s[n] = s;
    }
    __syncthreads();

    // ---- maha + log prob per (n,k) ----
    #pragma unroll
    for (int it = 0; it < 4; ++it) {
        const int pp = it * 256 + tid;
        const int n = pp & 31, k = pp >> 5;
        const float4* zp = (const float4*)&Gs[n][k * QQ];
        float corr = 0.f;
        #pragma unroll
        for (int qq = 0; qq < 4; ++qq) {
            const float4 z = zp[qq];
            const float d0 = z.x - w_s[k][qq * 4 + 0];
            const float d1 = z.y - w_s[k][qq * 4 + 1];
            const float d2 = z.z - w_s[k][qq * 4 + 2];
            const float d3 = z.w - w_s[k][qq * 4 + 3];
            corr = fmaf(d0, d0, corr); corr = fmaf(d1, d1, corr);
            corr = fmaf(d2, d2, corr); corr = fmaf(d3, d3, corr);
        }
        const float xmu = Gs[n][512 + k];
        // lp = constk' - 0.5*sx + xmu + 0.5*corr
        lps[n][k] = ck_s[k] - 0.5f * sx_s[n] + xmu + 0.5f * corr;
    }
    __syncthreads();

    // ---- logsumexp + output, one thread per row ----
    if (tid < 32) {
        const int n = tid;
        float m = -INFINITY;
        #pragma unroll
        for (int k = 0; k < KK; ++k) m = fmaxf(m, lps[n][k]);
        float sum = 0.f;
        #pragma unroll
        for (int k = 0; k < KK; ++k) sum += expf(lps[n][k] - m);
        const float lse = m + logf(sum);
        float4* o = (float4*)(out + (size_t)(r0 + n) * KK);
        #pragma unroll
        for (int k4 = 0; k4 < KK / 4; ++k4)
            o[k4] = make_float4(lps[n][4 * k4 + 0] - lse, lps[n][4 * k4 + 1] - lse,
                                lps[n][4 * k4 + 2] - lse, lps[n][4 * k4 + 3] - lse);
        out[(size_t)NN * KK + r0 + n] = lse;
    }
}

extern "C" void kernel_launch(void* const* d_in, const int* in_sizes, int n_in,
                              void* d_out, int out_size, void* d_ws, size_t ws_size,
                              hipStream_t stream) {
    const float* X       = (const float*)d_in[0];
    const float* log_pi  = (const float*)d_in[1];
    const float* mu      = (const float*)d_in[2];
    const float* Lambda  = (const float*)d_in[3];
    const float* log_psi = (const float*)d_in[4];
    float* out = (float*)d_out;

    unsigned short* Wb = (unsigned short*)d_ws;            // 8*36*64*8*2 = 294912 B
    float* constk2 = (float*)((char*)d_ws + 294912);       // 32 floats
    float* wvec    = constk2 + KK;                         // 512 floats

    mfa_setup_k<<<KK, 256, 0, stream>>>(log_pi, mu, Lambda, log_psi, Wb, constk2, wvec);
    mfa_gemm_fused<<<NN / 32, 256, 0, stream>>>(X, log_psi, Wb, constk2, wvec, out);
}

// Round 3
// 93.043 us; speedup vs baseline: 2.8109x; 1.0887x over previous
//
#include <hip/hip_runtime.h>
#include <math.h>

#define KK 32
#define DD 256
#define QQ 16
#define NN 8192
#define LOG2PI 1.8378770664093453f
#define NCT 36            // padded col-tiles: 576 cols = 512 z + 32 xmu + 32 pad
#define CPW 9             // col-tiles per wave (4 waves x 9 = 36)

typedef __attribute__((ext_vector_type(8))) short short8v;
typedef __attribute__((ext_vector_type(4))) float float4v;

__device__ __forceinline__ unsigned short f2bf(float f) {
    union { float f; unsigned int u; } v; v.f = f;
    unsigned int u = v.u;
    return (unsigned short)((u + 0x7FFFu + ((u >> 16) & 1u)) >> 16);  // RNE
}

// ---------------- Kernel 1: per-component precompute (one block per k) ----
// Wb frag layout (verified in R2): Wb[((kt*NCT+ct)*64+lane)*8+j] =
//   W[kt*32+(lane>>4)*8+j][ct*16+(lane&15)]
// W cols: [0,512): c=k*16+q -> T_k[q][d]; [512,544): mu[c-512][d]*ia[d]; rest 0.
__global__ __launch_bounds__(256) void mfa_setup_k(
    const float* __restrict__ log_pi,
    const float* __restrict__ mu,       // [K][D]
    const float* __restrict__ Lambda,   // [K][D][Q]
    const float* __restrict__ log_psi,  // [D]
    unsigned short* __restrict__ Wb,
    float* __restrict__ constk2,        // [K]
    float* __restrict__ wvec)           // [K][Q]
{
    __shared__ float inv_a_s[DD];
    __shared__ float Ls[DD][QQ];        // raw Lambda_k rows
    __shared__ float Lsia[DD][QQ];      // Lambda_k * inv_a
    __shared__ float Ms[QQ][QQ + 1];
    __shared__ float Lc[QQ][QQ + 1];    // Cholesky factor (lower)
    __shared__ float red_lg[4], red_m2[4], redq[4][QQ];
    __shared__ float sum_log_a_s, mu2a_s, ld_s;

    const int k = blockIdx.x;
    const int tid = threadIdx.x;
    const int wv = tid >> 6;

    const float a = expf(log_psi[tid]) + 1e-6f + 1e-5f;
    const float ia = 1.0f / a;
    inv_a_s[tid] = ia;
    const float mud = mu[k * DD + tid];

    float lg = logf(a);
    float m2 = mud * mud * ia;
    #pragma unroll
    for (int off = 32; off; off >>= 1) {
        lg += __shfl_down(lg, off, 64);
        m2 += __shfl_down(m2, off, 64);
    }
    if ((tid & 63) == 0) { red_lg[wv] = lg; red_m2[wv] = m2; }

    // stage Lambda_k
    const float* Lk = Lambda + (size_t)k * DD * QQ;
    for (int i = tid; i < DD * QQ; i += 256) Ls[i >> 4][i & 15] = Lk[i];
    __syncthreads();

    // Lsia row (own d = tid)
    #pragma unroll
    for (int q = 0; q < QQ; ++q) Lsia[tid][q] = Ls[tid][q] * ia;
    if (tid == 0) {
        sum_log_a_s = red_lg[0] + red_lg[1] + red_lg[2] + red_lg[3];
        mu2a_s      = red_m2[0] + red_m2[1] + red_m2[2] + red_m2[3];
    }
    __syncthreads();

    // M = I + Lambda^T diag(ia) Lambda  (q1-read is a 16-lane broadcast)
    {
        const int q1 = tid >> 4, q2 = tid & 15;
        float b = 0.f;
        for (int d = 0; d < DD; ++d) b = fmaf(Lsia[d][q1], Ls[d][q2], b);
        Ms[q1][q2] = b + (q1 == q2 ? 1.0f : 0.0f);
    }
    __syncthreads();

    // Register-resident shuffle Cholesky, lanes 0..15 of wave 0, no barriers.
    if (tid < QQ) {
        const int i = tid;
        float mrow[QQ];
        #pragma unroll
        for (int j = 0; j < QQ; ++j) mrow[j] = Ms[i][j];
        float l[QQ];
        float ldiag = 0.f;
        #pragma unroll
        for (int j = 0; j < QQ; ++j) {
            float s = mrow[j];
            #pragma unroll
            for (int t = 0; t < QQ; ++t) {
                if (t < j) s = fmaf(-l[t], __shfl(l[t], j, 64), s);
            }
            const float piv = __shfl(s, j, 64);
            const float ljj = sqrtf(piv);
            const float val = s / ljj;
            l[j] = (i == j) ? ljj : ((i > j) ? val : 0.f);
            if (i == j) ldiag = logf(ljj);
        }
        #pragma unroll
        for (int j = 0; j < QQ; ++j) Lc[i][j] = l[j];
        // reduce sum log diag over 16 lanes
        #pragma unroll
        for (int mask = 1; mask <= 8; mask <<= 1) ldiag += __shfl_xor(ldiag, mask, 64);
        if (i == 0) ld_s = ldiag;
    }
    __syncthreads();

    if (tid == 0) {
        const float logdetC = sum_log_a_s + 2.0f * ld_s;
        constk2[k] = log_pi[k] - 0.5f * ((float)DD * LOG2PI + logdetC + mu2a_s);
    }

    // Forward-solve L y = Lambda[d,:]^T per thread d; tv = y * ia[d].
    // Lc reads are wave-uniform broadcasts; y[] in registers (static unroll).
    float tv[QQ];
    {
        float y[QQ];
        #pragma unroll
        for (int q = 0; q < QQ; ++q) {
            float s = Ls[tid][q];
            #pragma unroll
            for (int m = 0; m < QQ; ++m) {
                if (m < q) s = fmaf(-Lc[q][m], y[m], s);
            }
            y[q] = s / Lc[q][q];
        }
        #pragma unroll
        for (int q = 0; q < QQ; ++q) tv[q] = y[q] * ia;
    }

    // w_kq = sum_d tv[q] * mu[k][d]
    #pragma unroll
    for (int q = 0; q < QQ; ++q) {
        float v = tv[q] * mud;
        #pragma unroll
        for (int off = 32; off; off >>= 1) v += __shfl_down(v, off, 64);
        if ((tid & 63) == 0) redq[wv][q] = v;
    }
    __syncthreads();
    if (tid < QQ) wvec[k * QQ + tid] = redq[0][tid] + redq[1][tid] + redq[2][tid] + redq[3][tid];

    // scatter into Wb fragment layout (bf16) — identical to R2 (verified)
    {
        const int d = tid;
        const int kt = d >> 5, l_hi = (d >> 3) & 3, j = d & 7;
        #pragma unroll
        for (int q = 0; q < QQ; ++q) {
            const size_t idx = (((size_t)(kt * NCT + k) * 64) + l_hi * 16 + q) * 8 + j;
            Wb[idx] = f2bf(tv[q]);
        }
        const size_t idx = (((size_t)(kt * NCT + 32 + (k >> 4)) * 64) + l_hi * 16 + (k & 15)) * 8 + j;
        Wb[idx] = f2bf(mud * ia);
    }
    if (k < 2) {
        for (int i = tid; i < 512; i += 256) {
            const int kt = i >> 6, lane = i & 63;
            const size_t base = ((size_t)(kt * NCT + 34 + k) * 64 + lane) * 8;
            #pragma unroll
            for (int j = 0; j < 8; ++j) Wb[base + j] = 0;
        }
    }
}

// ---------------- Kernel 2: fused GEMM + in-register epilogue ------------
// Block: 16 rows x 576 cols, 4 waves x 9 col-tiles; grid 512 (2 blocks/CU).
__global__ __launch_bounds__(256) void mfa_gemm_fused(
    const float* __restrict__ X,        // [N][D]
    const float* __restrict__ log_psi,  // [D]
    const unsigned short* __restrict__ Wb,
    const float* __restrict__ constk2,
    const float* __restrict__ wvec,     // [K][Q]
    float* __restrict__ out)            // [N*K] then [N]
{
    __shared__ short As[8 * 64 * 8];    // bf16 A-frags, 8 KB
    __shared__ float inv_a_s[DD];
    __shared__ float w_s[KK][QQ];
    __shared__ float ck_s[KK];
    __shared__ float sx_s[16];
    __shared__ float corr_s[16][KK + 1];
    __shared__ float xmu_s[16][KK + 1];

    const int tid = threadIdx.x;
    const int lane = tid & 63, wv = tid >> 6;
    const int r0 = blockIdx.x * 16;

    inv_a_s[tid] = 1.0f / (expf(log_psi[tid]) + 1e-6f + 1e-5f);
    if (tid < KK) ck_s[tid] = constk2[tid];
    for (int i = tid; i < KK * QQ; i += 256) ((float*)w_s)[i] = wvec[i];

    // stage X tile -> bf16 A-frag layout in LDS (convert once per block)
    #pragma unroll
    for (int rep = 0; rep < 2; ++rep) {
        const int c = tid + rep * 256;          // chunk = (kt, lane_c)
        const int kt = c >> 6, lc = c & 63;
        const int m = lc & 15, d0 = kt * 32 + ((lc >> 4) & 3) * 8;
        const float4* xp = (const float4*)(X + (size_t)(r0 + m) * DD + d0);
        const float4 x0 = xp[0], x1 = xp[1];
        short8v av;
        av[0] = (short)f2bf(x0.x); av[1] = (short)f2bf(x0.y);
        av[2] = (short)f2bf(x0.z); av[3] = (short)f2bf(x0.w);
        av[4] = (short)f2bf(x1.x); av[5] = (short)f2bf(x1.y);
        av[6] = (short)f2bf(x1.z); av[7] = (short)f2bf(x1.w);
        *(short8v*)&As[(size_t)(kt * 64 + lc) * 8] = av;
    }
    __syncthreads();

    // MFMA K-loop: A from LDS (ds_read_b128), B from global (L2-resident)
    const int sw = wv * CPW;
    float4v acc[CPW];
    #pragma unroll
    for (int ct = 0; ct < CPW; ++ct)
        #pragma unroll
        for (int r = 0; r < 4; ++r) acc[ct][r] = 0.f;

    #pragma unroll
    for (int kt = 0; kt < 8; ++kt) {
        const short8v a = *(const short8v*)&As[(size_t)(kt * 64 + lane) * 8];
        const short8v* Wp = (const short8v*)Wb + (size_t)(kt * NCT + sw) * 64 + lane;
        #pragma unroll
        for (int ct = 0; ct < CPW; ++ct) {
            const short8v bf = Wp[ct * 64];
            acc[ct] = __builtin_amdgcn_mfma_f32_16x16x32_bf16(a, bf, acc[ct], 0, 0, 0);
        }
    }

    // sx[n] = sum_d x^2 * inv_a (f32): 16 threads per row
    {
        const int n = tid >> 4, part = tid & 15;
        const float4* xp = (const float4*)(X + (size_t)(r0 + n) * DD + part * 16);
        float s = 0.f;
        #pragma unroll
        for (int i = 0; i < 4; ++i) {
            const float4 v = xp[i];
            const int d = part * 16 + i * 4;
            s = fmaf(v.x * inv_a_s[d + 0], v.x, s);
            s = fmaf(v.y * inv_a_s[d + 1], v.y, s);
            s = fmaf(v.z * inv_a_s[d + 2], v.z, s);
            s = fmaf(v.w * inv_a_s[d + 3], v.w, s);
        }
        s += __shfl_xor(s, 1, 64);
        s += __shfl_xor(s, 2, 64);
        s += __shfl_xor(s, 4, 64);
        s += __shfl_xor(s, 8, 64);
        if (part == 0) sx_s[n] = s;
    }

    // in-register epilogue: corr via 16-lane butterfly; xmu direct
    #pragma unroll
    for (int ct = 0; ct < CPW; ++ct) {
        const int cti = sw + ct;                // wave-uniform
        if (cti < 32) {
            const float w = w_s[cti][lane & 15];
            float q0 = acc[ct][0] - w, q1 = acc[ct][1] - w,
                  q2 = acc[ct][2] - w, q3 = acc[ct][3] - w;
            q0 *= q0; q1 *= q1; q2 *= q2; q3 *= q3;
            #pragma unroll
            for (int mask = 1; mask <= 8; mask <<= 1) {
                q0 += __shfl_xor(q0, mask, 64);
                q1 += __shfl_xor(q1, mask, 64);
                q2 += __shfl_xor(q2, mask, 64);
                q3 += __shfl_xor(q3, mask, 64);
            }
            if ((lane & 15) == 0) {
                const int nb = (lane >> 4) * 4;
                corr_s[nb + 0][cti] = q0; corr_s[nb + 1][cti] = q1;
                corr_s[nb + 2][cti] = q2; corr_s[nb + 3][cti] = q3;
            }
        } else if (cti < 34) {
            const int kk = (cti - 32) * 16 + (lane & 15);
            const int nb = (lane >> 4) * 4;
            xmu_s[nb + 0][kk] = acc[ct][0]; xmu_s[nb + 1][kk] = acc[ct][1];
            xmu_s[nb + 2][kk] = acc[ct][2]; xmu_s[nb + 3][kk] = acc[ct][3];
        }
    }
    __syncthreads();

    // logsumexp + output, one thread per row
    if (tid < 16) {
        const int n = tid;
        const float sxh = 0.5f * sx_s[n];
        float lp[KK];
        float m = -INFINITY;
        #pragma unroll
        for (int k = 0; k < KK; ++k) {
            const float v = ck_s[k] - sxh + xmu_s[n][k] + 0.5f * corr_s[n][k];
            lp[k] = v;
            m = fmaxf(m, v);
        }
        float sum = 0.f;
        #pragma unroll
        for (int k = 0; k < KK; ++k) sum += expf(lp[k] - m);
        const float lse = m + logf(sum);
        float4* o = (float4*)(out + (size_t)(r0 + n) * KK);
        #pragma unroll
        for (int k4 = 0; k4 < KK / 4; ++k4)
            o[k4] = make_float4(lp[4 * k4 + 0] - lse, lp[4 * k4 + 1] - lse,
                                lp[4 * k4 + 2] - lse, lp[4 * k4 + 3] - lse);
        out[(size_t)NN * KK + r0 + n] = lse;
    }
}

extern "C" void kernel_launch(void* const* d_in, const int* in_sizes, int n_in,
                              void* d_out, int out_size, void* d_ws, size_t ws_size,
                              hipStream_t stream) {
    const float* X       = (const float*)d_in[0];
    const float* log_pi  = (const float*)d_in[1];
    const float* mu      = (const float*)d_in[2];
    const float* Lambda  = (const float*)d_in[3];
    const float* log_psi = (const float*)d_in[4];
    float* out = (float*)d_out;

    unsigned short* Wb = (unsigned short*)d_ws;            // 8*36*64*8*2 = 294912 B
    float* constk2 = (float*)((char*)d_ws + 294912);
    float* wvec    = constk2 + KK;

    mfa_setup_k<<<KK, 256, 0, stream>>>(log_pi, mu, Lambda, log_psi, Wb, constk2, wvec);
    mfa_gemm_fused<<<NN / 16, 256, 0, stream>>>(X, log_psi, Wb, constk2, wvec, out);
}